// Round 3
// baseline (220.196 us; speedup 1.0000x reference)
//
#include <hip/hip_runtime.h>
#include <hip/hip_bf16.h>
#include <stdint.h>

#define B_ 2048
#define L_ 128
#define V_ 50000
#define D_ 128

typedef __attribute__((ext_vector_type(8))) short bf16x8;
typedef __attribute__((ext_vector_type(8))) unsigned short ushort8;
typedef __attribute__((ext_vector_type(4))) float f32x4;

__device__ inline unsigned short f2bf(float f) {
    union { float f; uint32_t u; } v; v.f = f;
    uint32_t u = v.u + 0x7FFFu + ((v.u >> 16) & 1u);   // RNE
    return (unsigned short)(u >> 16);
}
__device__ inline float bf2f(unsigned short h) {
    union { uint32_t u; float f; } v; v.u = ((uint32_t)h) << 16;
    return v.f;
}
__device__ inline float tanh_fast(float x) {
    float xc = fminf(fmaxf(x, -15.f), 15.f);
    float z = __expf(2.f * xc);
    return (z - 1.f) / (z + 1.f);
}

// ---------------- kernel 0: fused emb->bf16 convert + aT transpose ----------------
// blocks 0..3124: convert 2048 emb elems each; block 3125: build aT (16K elems)
__global__ __launch_bounds__(256) void k_pre(const float* __restrict__ emb,
                                             unsigned short* __restrict__ emb_bf,
                                             const float* __restrict__ a,
                                             unsigned short* __restrict__ aT,
                                             int use_bf) {
    int bid = blockIdx.x;
    if (use_bf && bid < 3125) {
        size_t i = ((size_t)bid * 256 + threadIdx.x) * 8;  // 6,400,000 elems exact
        float4 x0 = *(const float4*)(emb + i);
        float4 x1 = *(const float4*)(emb + i + 4);
        ushort8 v;
        v[0] = f2bf(x0.x); v[1] = f2bf(x0.y); v[2] = f2bf(x0.z); v[3] = f2bf(x0.w);
        v[4] = f2bf(x1.x); v[5] = f2bf(x1.y); v[6] = f2bf(x1.z); v[7] = f2bf(x1.w);
        *(ushort8*)(emb_bf + i) = v;
    } else if (!use_bf || bid == 3125) {
#pragma unroll 4
        for (int j = threadIdx.x; j < 16384; j += 256) {
            int d = j >> 7, n = j & 127;
            aT[n * 128 + d] = f2bf(a[d * 128 + n]);
        }
    }
}

// ---------------- kernel 1: user_bf16[b][d] ----------------
// one block per b; 256 threads = 4 waves; aT fragments read straight from L1/L2
__global__ __launch_bounds__(256) void k_user(
    const int* __restrict__ ids, const int* __restrict__ msk,
    const float* __restrict__ emb, const unsigned short* __restrict__ emb_bf,
    const unsigned short* __restrict__ aT,
    const float* __restrict__ bvec, unsigned short* __restrict__ user_bf,
    int use_bf) {
    __shared__ __align__(16) unsigned short lh[128 * 128];  // h tile, swizzled (32KB)
    __shared__ float l_e[128];
    __shared__ float l_attn[128];
    __shared__ float l_p[256];

    int b = blockIdx.x;
    int t = threadIdx.x;

    // stage h = emb[ids[b,:]] -> bf16 LDS (XOR swizzle on ushort index: c ^ ((row&7)<<3))
    {
        int row = t >> 1, half = t & 1;
        int id = ids[b * L_ + row];
        if (use_bf) {
            const unsigned short* src = emb_bf + (size_t)id * D_ + half * 64;
#pragma unroll
            for (int q = 0; q < 8; ++q) {
                ushort8 v = *(const ushort8*)(src + q * 8);
                int c = half * 64 + q * 8;
                *(ushort8*)&lh[row * 128 + (c ^ ((row & 7) << 3))] = v;
            }
        } else {
            const float* src = emb + (size_t)id * D_ + half * 64;
#pragma unroll
            for (int q = 0; q < 8; ++q) {
                float4 x0 = *(const float4*)(src + q * 8);
                float4 x1 = *(const float4*)(src + q * 8 + 4);
                ushort8 v;
                v[0] = f2bf(x0.x); v[1] = f2bf(x0.y); v[2] = f2bf(x0.z); v[3] = f2bf(x0.w);
                v[4] = f2bf(x1.x); v[5] = f2bf(x1.y); v[6] = f2bf(x1.z); v[7] = f2bf(x1.w);
                int c = half * 64 + q * 8;
                *(ushort8*)&lh[row * 128 + (c ^ ((row & 7) << 3))] = v;
            }
        }
    }
    __syncthreads();

    int wave = t >> 6, lane = t & 63, lo = lane & 15, hi = lane >> 4;

    // t = h @ a  via mfma 16x16x32 (M=128 rows of h, N=128, K=128)
    f32x4 acc[2][8] = {};
#pragma unroll
    for (int kk = 0; kk < 4; ++kk) {
        int kc = kk * 32 + hi * 8;   // k element offset
        bf16x8 afr[2];
#pragma unroll
        for (int mi = 0; mi < 2; ++mi) {
            int row = wave * 32 + mi * 16 + lo;
            afr[mi] = *(const bf16x8*)&lh[row * 128 + (kc ^ ((row & 7) << 3))];
        }
#pragma unroll
        for (int nj = 0; nj < 8; ++nj) {
            int col = nj * 16 + lo;
            bf16x8 bfr = *(const bf16x8*)(aT + col * 128 + kc);   // L1-resident (32KB)
            acc[0][nj] = __builtin_amdgcn_mfma_f32_16x16x32_bf16(afr[0], bfr, acc[0][nj], 0, 0, 0);
            acc[1][nj] = __builtin_amdgcn_mfma_f32_16x16x32_bf16(afr[1], bfr, acc[1][nj], 0, 0, 0);
        }
    }

    // e[row] = sum_n tanh(t[row,n]) * bvec[n] ; C/D layout: col=lo, row=hi*4+reg
    float bv[8];
#pragma unroll
    for (int nj = 0; nj < 8; ++nj) bv[nj] = bvec[nj * 16 + lo];
#pragma unroll
    for (int mi = 0; mi < 2; ++mi) {
#pragma unroll
        for (int reg = 0; reg < 4; ++reg) {
            float p = 0.f;
#pragma unroll
            for (int nj = 0; nj < 8; ++nj) p += tanh_fast(acc[mi][nj][reg]) * bv[nj];
            p += __shfl_xor(p, 1); p += __shfl_xor(p, 2);
            p += __shfl_xor(p, 4); p += __shfl_xor(p, 8);
            int row = wave * 32 + mi * 16 + hi * 4 + reg;
            if (lo == 0) l_e[row] = p;
        }
    }
    __syncthreads();

    if (t < 128) {
        float e = l_e[t];
        float at = 0.f;
        if (msk[b * L_ + t]) at = 1.f / (1.f + __expf(-e));
        l_attn[t] = at;
    }
    __syncthreads();

    // user[d] = sum_l attn[l] * h[l][d]
    {
        int d = t & 127, half = t >> 7;
        float s = 0.f;
#pragma unroll 8
        for (int l = half * 64; l < half * 64 + 64; ++l)
            s += l_attn[l] * bf2f(lh[l * 128 + (d ^ ((l & 7) << 3))]);
        l_p[t] = s;
    }
    __syncthreads();
    if (t < 128) {
        float u = l_p[t] + l_p[t + 128];
        user_bf[b * 128 + t] = f2bf(u);
    }
}

// ---------------- kernel 2: logits = user_bf16 @ emb^T + bias ----------------
// grid (4, 391): each block stages one 128-col emb tile ONCE, loops 4 M-tiles.
// MFMA operands swapped: mfma(emb_frag, user_frag) so each lane's 4 accumulator
// regs are 4 consecutive vocab columns -> float4 NONTEMPORAL stores (bypass L2,
// avoid read-for-ownership on the 410MB streaming output).
__global__ __launch_bounds__(256) void k_logits(
    const unsigned short* __restrict__ user_bf, const float* __restrict__ emb,
    const unsigned short* __restrict__ emb_bf,
    const float* __restrict__ bias, float* __restrict__ out, int use_bf) {
    __shared__ __align__(16) unsigned short lb[128 * 128];  // emb tile [n][k] bf16 swizzled (32KB)

    int t = threadIdx.x;
    int m_base = blockIdx.x * 512;           // 4 chunks x 4 tiles of 128
    int n0 = blockIdx.y * 128;

    // stage B tile: emb rows n0..n0+127 -> bf16 LDS (guard tail rows -> 0)
    {
        int r = t >> 1, half = t & 1;
        int n = n0 + r;
        if (n < V_) {
            if (use_bf) {
                const unsigned short* src = emb_bf + (size_t)n * D_ + half * 64;
#pragma unroll
                for (int q = 0; q < 8; ++q) {
                    ushort8 v = *(const ushort8*)(src + q * 8);
                    int c = half * 64 + q * 8;
                    *(ushort8*)&lb[r * 128 + (c ^ ((r & 7) << 3))] = v;
                }
            } else {
                const float* src = emb + (size_t)n * D_ + half * 64;
#pragma unroll
                for (int q = 0; q < 8; ++q) {
                    float4 x0 = *(const float4*)(src + q * 8);
                    float4 x1 = *(const float4*)(src + q * 8 + 4);
                    ushort8 v;
                    v[0] = f2bf(x0.x); v[1] = f2bf(x0.y); v[2] = f2bf(x0.z); v[3] = f2bf(x0.w);
                    v[4] = f2bf(x1.x); v[5] = f2bf(x1.y); v[6] = f2bf(x1.z); v[7] = f2bf(x1.w);
                    int c = half * 64 + q * 8;
                    *(ushort8*)&lb[r * 128 + (c ^ ((r & 7) << 3))] = v;
                }
            }
        } else {
            ushort8 z = {0, 0, 0, 0, 0, 0, 0, 0};
#pragma unroll
            for (int q = 0; q < 8; ++q) {
                int c = half * 64 + q * 8;
                *(ushort8*)&lb[r * 128 + (c ^ ((r & 7) << 3))] = z;
            }
        }
    }

    int wave = t >> 6, lane = t & 63, lo = lane & 15, hi = lane >> 4;

    // bias: n = n0 + nj*16 + hi*4 + reg ; amortized over all m-tiles
    float4 bb[8];
#pragma unroll
    for (int nj = 0; nj < 8; ++nj) {
        int n = n0 + nj * 16 + hi * 4;
        if (n + 3 < V_) {
            bb[nj] = *(const float4*)(bias + n);
        } else {
            bb[nj].x = (n + 0 < V_) ? bias[n + 0] : 0.f;
            bb[nj].y = (n + 1 < V_) ? bias[n + 1] : 0.f;
            bb[nj].z = (n + 2 < V_) ? bias[n + 2] : 0.f;
            bb[nj].w = (n + 3 < V_) ? bias[n + 3] : 0.f;
        }
    }
    __syncthreads();

#pragma unroll 1
    for (int mt = 0; mt < 4; ++mt) {
        int m0 = m_base + mt * 128;

        // A (user) fragments from global: 512KB total, L2-resident
        bf16x8 afr[2][4];
#pragma unroll
        for (int mi = 0; mi < 2; ++mi) {
            const unsigned short* ap = user_bf + (size_t)(m0 + wave * 32 + mi * 16 + lo) * 128;
#pragma unroll
            for (int kk = 0; kk < 4; ++kk)
                afr[mi][kk] = *(const bf16x8*)(ap + kk * 32 + hi * 8);
        }

        f32x4 acc[2][8] = {};
#pragma unroll
        for (int kk = 0; kk < 4; ++kk) {
            int kc = kk * 32 + hi * 8;
#pragma unroll
            for (int nj = 0; nj < 8; ++nj) {
                int col = nj * 16 + lo;
                bf16x8 bfr = *(const bf16x8*)&lb[col * 128 + (kc ^ ((col & 7) << 3))];
                // swapped: D[emb_idx][user_idx] -> lane holds 4 consecutive vocab cols
                acc[0][nj] = __builtin_amdgcn_mfma_f32_16x16x32_bf16(bfr, afr[0][kk], acc[0][nj], 0, 0, 0);
                acc[1][nj] = __builtin_amdgcn_mfma_f32_16x16x32_bf16(bfr, afr[1][kk], acc[1][nj], 0, 0, 0);
            }
        }

        // epilogue: row b from lo, 4 consecutive n per lane -> nontemporal float4
#pragma unroll
        for (int mi = 0; mi < 2; ++mi) {
            int b = m0 + wave * 32 + mi * 16 + lo;
#pragma unroll
            for (int nj = 0; nj < 8; ++nj) {
                int n = n0 + nj * 16 + hi * 4;
                f32x4 o;
                o[0] = acc[mi][nj][0] + bb[nj].x;
                o[1] = acc[mi][nj][1] + bb[nj].y;
                o[2] = acc[mi][nj][2] + bb[nj].z;
                o[3] = acc[mi][nj][3] + bb[nj].w;
                if (n + 3 < V_) {
                    __builtin_nontemporal_store(o, (f32x4*)(out + (size_t)b * V_ + n));
                } else {
                    if (n + 0 < V_) __builtin_nontemporal_store(o[0], out + (size_t)b * V_ + n + 0);
                    if (n + 1 < V_) __builtin_nontemporal_store(o[1], out + (size_t)b * V_ + n + 1);
                    if (n + 2 < V_) __builtin_nontemporal_store(o[2], out + (size_t)b * V_ + n + 2);
                    if (n + 3 < V_) __builtin_nontemporal_store(o[3], out + (size_t)b * V_ + n + 3);
                }
            }
        }
    }
}

extern "C" void kernel_launch(void* const* d_in, const int* in_sizes, int n_in,
                              void* d_out, int out_size, void* d_ws, size_t ws_size,
                              hipStream_t stream) {
    const int* ids      = (const int*)d_in[0];
    const int* msk      = (const int*)d_in[1];
    const float* emb    = (const float*)d_in[2];
    const float* attn_a = (const float*)d_in[3];
    const float* attn_b = (const float*)d_in[4];
    const float* rbias  = (const float*)d_in[5];
    float* out = (float*)d_out;

    unsigned short* aT      = (unsigned short*)d_ws;                     // 32 KB
    unsigned short* user_bf = (unsigned short*)((char*)d_ws + 32768);    // 512 KB
    unsigned short* emb_bf  = (unsigned short*)((char*)d_ws + 32768 + 524288);  // 12.8 MB
    int use_bf = (ws_size >= (size_t)(32768 + 524288 + 12800000)) ? 1 : 0;

    k_pre<<<use_bf ? 3126 : 1, 256, 0, stream>>>(emb, emb_bf, attn_a, aT, use_bf);
    k_user<<<2048, 256, 0, stream>>>(ids, msk, emb, emb_bf, aT, attn_b, user_bf, use_bf);
    k_logits<<<dim3(4, (V_ + 127) / 128), 256, 0, stream>>>(user_bf, emb, emb_bf, rbias, out, use_bf);
}